// Round 1
// baseline (461.766 us; speedup 1.0000x reference)
//
#include <hip/hip_runtime.h>

// Problem constants (B=8, T=20, C=1, H=512, W=512)
#define FRAMES 160
#define HH 512
#define WW 512
#define OH 506          // valid output rows (512-6)
#define STRIPS 8
#define STRIP_ROWS 64   // 7 strips of 64 + 1 strip of 58 = 506
#define NTOT 41943040   // 8*20*1*512*512
#define REC_BLOCKS 1280

// ws float layout: [0,1280) rec_abs partials; [1280,2560) rec_sq; [2560,3840) ssim
#define WS_ABS 0
#define WS_SQ 1280
#define WS_SSIM 2560

__device__ __forceinline__ float ssim_val(float Sx, float Sy, float Sxx,
                                          float Syy, float Sxy) {
  const float inv_np = 1.0f / 49.0f;
  const float cov = 49.0f / 48.0f;
  const float C1 = 6.5025f;    // (0.01*255)^2
  const float C2 = 58.5225f;   // (0.03*255)^2
  float ux = Sx * inv_np, uy = Sy * inv_np;
  float uxx = Sxx * inv_np, uyy = Syy * inv_np, uxy = Sxy * inv_np;
  float vx = cov * (uxx - ux * ux);
  float vy = cov * (uyy - uy * uy);
  float vxy = cov * (uxy - ux * uy);
  float A1 = 2.0f * ux * uy + C1;
  float A2 = 2.0f * vxy + C2;
  float B1 = ux * ux + uy * uy + C1;
  float B2 = vx + vy + C2;
  return (A1 * A2) / (B1 * B2);
}

__global__ __launch_bounds__(256) void rec_kernel(
    const float* __restrict__ a, const float* __restrict__ b,
    float* __restrict__ ws, int n4) {
  const int tid = blockIdx.x * 256 + threadIdx.x;
  const int stride = gridDim.x * 256;
  const float4* __restrict__ a4 = (const float4*)a;
  const float4* __restrict__ b4 = (const float4*)b;
  float sabs = 0.0f, ssq = 0.0f;
  for (int i = tid; i < n4; i += stride) {
    float4 av = a4[i];
    float4 bv = b4[i];
    float dx = av.x - bv.x, dy = av.y - bv.y;
    float dz = av.z - bv.z, dw = av.w - bv.w;
    sabs += fabsf(dx) + fabsf(dy) + fabsf(dz) + fabsf(dw);
    ssq += dx * dx + dy * dy + dz * dz + dw * dw;
  }
  // wave(64) shuffle reduce both quantities
  #pragma unroll
  for (int off = 32; off > 0; off >>= 1) {
    sabs += __shfl_down(sabs, off, 64);
    ssq += __shfl_down(ssq, off, 64);
  }
  __shared__ float la[4], lb[4];
  const int lane = threadIdx.x & 63, wave = threadIdx.x >> 6;
  if (lane == 0) { la[wave] = sabs; lb[wave] = ssq; }
  __syncthreads();
  if (threadIdx.x == 0) {
    ws[WS_ABS + blockIdx.x] = la[0] + la[1] + la[2] + la[3];
    ws[WS_SQ + blockIdx.x] = lb[0] + lb[1] + lb[2] + lb[3];
  }
}

// grid: (STRIPS, FRAMES); block: 256 threads; thread t owns columns 2t, 2t+1.
__global__ __launch_bounds__(256) void ssim_kernel(
    const float* __restrict__ g, const float* __restrict__ t,
    float* __restrict__ ws) {
  const int frame = blockIdx.y;
  const int strip = blockIdx.x;
  const int row0 = strip * STRIP_ROWS;
  const int rows = min(STRIP_ROWS, OH - row0);
  const int tid = threadIdx.x;
  const int c2 = tid * 2;
  const float* __restrict__ gf = g + (size_t)frame * (HH * WW);
  const float* __restrict__ tf = t + (size_t)frame * (HH * WW);

  __shared__ float sx[512], sy[512], sxx[512], syy[512], sxy[512];

  // 7-row register ring buffers (shift-down, fully static indexing)
  float2 xr[7], yr[7];
  #pragma unroll
  for (int i = 0; i < 6; ++i) {
    float2 gv = *(const float2*)(gf + (row0 + i) * WW + c2);
    float2 tv = *(const float2*)(tf + (row0 + i) * WW + c2);
    xr[i] = make_float2(gv.x * 255.0f, gv.y * 255.0f);
    yr[i] = make_float2(tv.x * 255.0f, tv.y * 255.0f);
  }

  float ssum = 0.0f;
  for (int r = 0; r < rows; ++r) {
    {
      float2 gv = *(const float2*)(gf + (row0 + r + 6) * WW + c2);
      float2 tv = *(const float2*)(tf + (row0 + r + 6) * WW + c2);
      xr[6] = make_float2(gv.x * 255.0f, gv.y * 255.0f);
      yr[6] = make_float2(tv.x * 255.0f, tv.y * 255.0f);
    }
    // column sums over the 7 rows (recompute each row: no drift)
    float2 csx = make_float2(0.f, 0.f), csy = make_float2(0.f, 0.f);
    float2 csxx = make_float2(0.f, 0.f), csyy = make_float2(0.f, 0.f);
    float2 csxy = make_float2(0.f, 0.f);
    #pragma unroll
    for (int i = 0; i < 7; ++i) {
      csx.x += xr[i].x;            csx.y += xr[i].y;
      csy.x += yr[i].x;            csy.y += yr[i].y;
      csxx.x += xr[i].x * xr[i].x; csxx.y += xr[i].y * xr[i].y;
      csyy.x += yr[i].x * yr[i].x; csyy.y += yr[i].y * yr[i].y;
      csxy.x += xr[i].x * yr[i].x; csxy.y += xr[i].y * yr[i].y;
    }
    ((float2*)sx)[tid] = csx;
    ((float2*)sy)[tid] = csy;
    ((float2*)sxx)[tid] = csxx;
    ((float2*)syy)[tid] = csyy;
    ((float2*)sxy)[tid] = csxy;
    __syncthreads();
    if (tid < 253) {  // 506 output columns = 2 per thread for threads 0..252
      float wx = 0.f, wy = 0.f, wxx = 0.f, wyy = 0.f, wxy = 0.f;
      #pragma unroll
      for (int j = 0; j < 7; ++j) {
        wx += sx[c2 + j];
        wy += sy[c2 + j];
        wxx += sxx[c2 + j];
        wyy += syy[c2 + j];
        wxy += sxy[c2 + j];
      }
      float wx1 = wx - sx[c2] + sx[c2 + 7];
      float wy1 = wy - sy[c2] + sy[c2 + 7];
      float wxx1 = wxx - sxx[c2] + sxx[c2 + 7];
      float wyy1 = wyy - syy[c2] + syy[c2 + 7];
      float wxy1 = wxy - sxy[c2] + sxy[c2 + 7];
      ssum += ssim_val(wx, wy, wxx, wyy, wxy);
      ssum += ssim_val(wx1, wy1, wxx1, wyy1, wxy1);
    }
    __syncthreads();
    #pragma unroll
    for (int i = 0; i < 6; ++i) { xr[i] = xr[i + 1]; yr[i] = yr[i + 1]; }
  }

  // block reduce ssum
  #pragma unroll
  for (int off = 32; off > 0; off >>= 1) ssum += __shfl_down(ssum, off, 64);
  __syncthreads();  // sx reuse as scratch
  const int lane = tid & 63, wave = tid >> 6;
  if (lane == 0) sx[wave] = ssum;
  __syncthreads();
  if (tid == 0) {
    ws[WS_SSIM + blockIdx.y * STRIPS + blockIdx.x] =
        sx[0] + sx[1] + sx[2] + sx[3];
  }
}

__global__ __launch_bounds__(256) void finalize_kernel(
    const float* __restrict__ ws, const float* __restrict__ genD,
    float* __restrict__ out) {
  const int tid = threadIdx.x;
  float a = 0.f, b = 0.f, c = 0.f;
  for (int i = tid; i < REC_BLOCKS; i += 256) {
    a += ws[WS_ABS + i];
    b += ws[WS_SQ + i];
    c += ws[WS_SSIM + i];
  }
  #pragma unroll
  for (int off = 32; off > 0; off >>= 1) {
    a += __shfl_down(a, off, 64);
    b += __shfl_down(b, off, 64);
    c += __shfl_down(c, off, 64);
  }
  __shared__ float la[4], lb[4], lc[4];
  const int lane = tid & 63, wave = tid >> 6;
  if (lane == 0) { la[wave] = a; lb[wave] = b; lc[wave] = c; }
  __syncthreads();
  if (tid == 0) {
    a = la[0] + la[1] + la[2] + la[3];
    b = lb[0] + lb[1] + lb[2] + lb[3];
    c = lc[0] + lc[1] + lc[2] + lc[3];
    const float invN = 1.0f / (float)NTOT;
    float L_rec = a * invN + b * invN;
    float L_ssim = c / (160.0f * 506.0f * 506.0f);
    float d = 0.f;
    #pragma unroll
    for (int i = 0; i < 8; ++i) d += genD[i];
    float L_adv = -d / 8.0f;
    float L_total = L_rec + 0.01f * (1.0f - L_ssim) + 0.0001f * L_adv;
    out[0] = L_total;
    out[1] = L_rec;
    out[2] = L_ssim;
    out[3] = L_adv;
  }
}

extern "C" void kernel_launch(void* const* d_in, const int* in_sizes, int n_in,
                              void* d_out, int out_size, void* d_ws,
                              size_t ws_size, hipStream_t stream) {
  const float* gen_img = (const float*)d_in[0];
  const float* target = (const float*)d_in[1];
  const float* gen_D = (const float*)d_in[2];
  float* out = (float*)d_out;
  float* ws = (float*)d_ws;

  const int n4 = in_sizes[0] / 4;  // 10,485,760 float4s

  rec_kernel<<<REC_BLOCKS, 256, 0, stream>>>(gen_img, target, ws, n4);
  dim3 sgrid(STRIPS, FRAMES);
  ssim_kernel<<<sgrid, 256, 0, stream>>>(gen_img, target, ws);
  finalize_kernel<<<1, 256, 0, stream>>>(ws, gen_D, out);
}

// Round 2
// 367.619 us; speedup vs baseline: 1.2561x; 1.2561x over previous
//
#include <hip/hip_runtime.h>

// B=8, T=20, C=1, H=512, W=512
#define FRAMES 160
#define HH 512
#define WW 512
#define STRIPS 8
#define SROWS 64          // input rows owned per strip (all strips own 64)
#define NTOT 41943040     // 8*20*512*512
#define NBLK (STRIPS * FRAMES)  // 1280 blocks

// ws float layout: [0,NBLK) abs; [NBLK,2NBLK) sq; [2NBLK,3NBLK) ssim

// SSIM with raw [0,1) values: scale-invariance lets us fold the *255 into
// the constants: C1 = (0.01*255)^2/255^2 = 1e-4, C2 = 9e-4.
__device__ __forceinline__ float ssim_val(float Sx, float Sy, float Sxx,
                                          float Syy, float Sxy) {
  const float inv_np = 1.0f / 49.0f;
  const float cov = 49.0f / 48.0f;
  const float C1 = 1.0e-4f;
  const float C2 = 9.0e-4f;
  float ux = Sx * inv_np, uy = Sy * inv_np;
  float vx = cov * (Sxx * inv_np - ux * ux);
  float vy = cov * (Syy * inv_np - uy * uy);
  float vxy = cov * (Sxy * inv_np - ux * uy);
  float A1 = 2.0f * ux * uy + C1;
  float A2 = 2.0f * vxy + C2;
  float B1 = ux * ux + uy * uy + C1;
  float B2 = vx + vy + C2;
  return (A1 * A2) / (B1 * B2);
}

// grid (STRIPS, FRAMES), block 256. Thread t owns input cols 2t, 2t+1.
// Strips 0..6: 64 output rows; strip 7: 58 (total 506). Every strip owns
// exactly 64 *input* rows for the L_rec reduction (6 init + 58 streamed).
__global__ __launch_bounds__(256) void fused_kernel(
    const float* __restrict__ g, const float* __restrict__ t,
    float* __restrict__ ws) {
  const int strip = blockIdx.x;
  const int frame = blockIdx.y;
  const int row0 = strip * SROWS;
  const int rows = (strip == STRIPS - 1) ? 58 : 64;
  const int tid = threadIdx.x;
  const float* __restrict__ gf = g + (size_t)frame * (HH * WW) + tid * 2;
  const float* __restrict__ tf = t + (size_t)frame * (HH * WW) + tid * 2;

  // LDS: per array, per thread: (cs.x, p = cs.x + cs.y). Double-buffered.
  __shared__ float2 buf[2][5][256];

  float2 xr[6], yr[6];  // raw ring: rows r..r+5 at loop entry
  float2 Sx = {0.f, 0.f}, Sy = {0.f, 0.f};
  float2 Sxx = {0.f, 0.f}, Syy = {0.f, 0.f}, Sxy = {0.f, 0.f};
  float sabs = 0.f, ssq = 0.f, ssum = 0.f;

  #pragma unroll
  for (int i = 0; i < 6; ++i) {
    float2 xv = *(const float2*)(gf + (row0 + i) * WW);
    float2 yv = *(const float2*)(tf + (row0 + i) * WW);
    xr[i] = xv; yr[i] = yv;
    float dx = xv.x - yv.x, dy = xv.y - yv.y;  // owned init rows -> L_rec
    sabs += fabsf(dx) + fabsf(dy);
    ssq += dx * dx + dy * dy;
    Sx.x += xv.x; Sx.y += xv.y;
    Sy.x += yv.x; Sy.y += yv.y;
    Sxx.x += xv.x * xv.x; Sxx.y += xv.y * xv.y;
    Syy.x += yv.x * yv.x; Syy.y += yv.y * yv.y;
    Sxy.x += xv.x * yv.x; Sxy.y += xv.y * yv.y;
  }

  for (int r = 0; r < rows; ++r) {
    float2 nx = *(const float2*)(gf + (row0 + r + 6) * WW);
    float2 ny = *(const float2*)(tf + (row0 + r + 6) * WW);
    if (r < 58) {  // streamed-row ownership for L_rec (exactly-once cover)
      float dx = nx.x - ny.x, dy = nx.y - ny.y;
      sabs += fabsf(dx) + fabsf(dy);
      ssq += dx * dx + dy * dy;
    }
    // S now covers rows r..r+6
    Sx.x += nx.x; Sx.y += nx.y;
    Sy.x += ny.x; Sy.y += ny.y;
    Sxx.x += nx.x * nx.x; Sxx.y += nx.y * nx.y;
    Syy.x += ny.x * ny.x; Syy.y += ny.y * ny.y;
    Sxy.x += nx.x * ny.x; Sxy.y += nx.y * ny.y;

    const int par = r & 1;
    float px = Sx.x + Sx.y, py = Sy.x + Sy.y;
    float pxx = Sxx.x + Sxx.y, pyy = Syy.x + Syy.y, pxy = Sxy.x + Sxy.y;
    buf[par][0][tid] = make_float2(Sx.x, px);
    buf[par][1][tid] = make_float2(Sy.x, py);
    buf[par][2][tid] = make_float2(Sxx.x, pxx);
    buf[par][3][tid] = make_float2(Syy.x, pyy);
    buf[par][4][tid] = make_float2(Sxy.x, pxy);
    __syncthreads();  // single barrier per row (parity double-buffer)

    if (tid < 253) {
      const float2* bx = buf[par][0];
      const float2* by = buf[par][1];
      const float2* bxx = buf[par][2];
      const float2* byy = buf[par][3];
      const float2* bxy = buf[par][4];
      float p1, p2; float2 f3;
      // array x
      p1 = bx[tid + 1].y; p2 = bx[tid + 2].y; f3 = bx[tid + 3];
      float wxe = px + p1 + p2 + f3.x;
      float wxo = Sx.y + p1 + p2 + f3.y;
      // array y
      p1 = by[tid + 1].y; p2 = by[tid + 2].y; f3 = by[tid + 3];
      float wye = py + p1 + p2 + f3.x;
      float wyo = Sy.y + p1 + p2 + f3.y;
      // array xx
      p1 = bxx[tid + 1].y; p2 = bxx[tid + 2].y; f3 = bxx[tid + 3];
      float wxxe = pxx + p1 + p2 + f3.x;
      float wxxo = Sxx.y + p1 + p2 + f3.y;
      // array yy
      p1 = byy[tid + 1].y; p2 = byy[tid + 2].y; f3 = byy[tid + 3];
      float wyye = pyy + p1 + p2 + f3.x;
      float wyyo = Syy.y + p1 + p2 + f3.y;
      // array xy
      p1 = bxy[tid + 1].y; p2 = bxy[tid + 2].y; f3 = bxy[tid + 3];
      float wxye = pxy + p1 + p2 + f3.x;
      float wxyo = Sxy.y + p1 + p2 + f3.y;

      ssum += ssim_val(wxe, wye, wxxe, wyye, wxye);
      ssum += ssim_val(wxo, wyo, wxxo, wyyo, wxyo);
    }

    // retire oldest row (row0+r) from the running sums
    float2 ox = xr[0], oy = yr[0];
    Sx.x -= ox.x; Sx.y -= ox.y;
    Sy.x -= oy.x; Sy.y -= oy.y;
    Sxx.x -= ox.x * ox.x; Sxx.y -= ox.y * ox.y;
    Syy.x -= oy.x * oy.x; Syy.y -= oy.y * oy.y;
    Sxy.x -= ox.x * oy.x; Sxy.y -= ox.y * oy.y;
    #pragma unroll
    for (int i = 0; i < 5; ++i) { xr[i] = xr[i + 1]; yr[i] = yr[i + 1]; }
    xr[5] = nx; yr[5] = ny;
  }

  // block reduce sabs / ssq / ssum
  #pragma unroll
  for (int off = 32; off > 0; off >>= 1) {
    sabs += __shfl_down(sabs, off, 64);
    ssq += __shfl_down(ssq, off, 64);
    ssum += __shfl_down(ssum, off, 64);
  }
  __syncthreads();
  float* scr = (float*)buf;  // safe: last loop reads used buf[1] (rows-1 odd)
  const int lane = tid & 63, wv = tid >> 6;
  if (lane == 0) { scr[wv] = sabs; scr[4 + wv] = ssq; scr[8 + wv] = ssum; }
  __syncthreads();
  if (tid == 0) {
    const int bid = blockIdx.y * STRIPS + blockIdx.x;
    ws[bid] = scr[0] + scr[1] + scr[2] + scr[3];
    ws[NBLK + bid] = scr[4] + scr[5] + scr[6] + scr[7];
    ws[2 * NBLK + bid] = scr[8] + scr[9] + scr[10] + scr[11];
  }
}

__global__ __launch_bounds__(256) void finalize_kernel(
    const float* __restrict__ ws, const float* __restrict__ genD,
    float* __restrict__ out) {
  const int tid = threadIdx.x;
  float a = 0.f, b = 0.f, c = 0.f;
  for (int i = tid; i < NBLK; i += 256) {
    a += ws[i];
    b += ws[NBLK + i];
    c += ws[2 * NBLK + i];
  }
  #pragma unroll
  for (int off = 32; off > 0; off >>= 1) {
    a += __shfl_down(a, off, 64);
    b += __shfl_down(b, off, 64);
    c += __shfl_down(c, off, 64);
  }
  __shared__ float la[4], lb[4], lc[4];
  const int lane = tid & 63, wv = tid >> 6;
  if (lane == 0) { la[wv] = a; lb[wv] = b; lc[wv] = c; }
  __syncthreads();
  if (tid == 0) {
    a = la[0] + la[1] + la[2] + la[3];
    b = lb[0] + lb[1] + lb[2] + lb[3];
    c = lc[0] + lc[1] + lc[2] + lc[3];
    const float invN = 1.0f / (float)NTOT;
    float L_rec = a * invN + b * invN;
    float L_ssim = c / (160.0f * 506.0f * 506.0f);
    float d = 0.f;
    #pragma unroll
    for (int i = 0; i < 8; ++i) d += genD[i];
    float L_adv = -d / 8.0f;
    float L_total = L_rec + 0.01f * (1.0f - L_ssim) + 0.0001f * L_adv;
    out[0] = L_total;
    out[1] = L_rec;
    out[2] = L_ssim;
    out[3] = L_adv;
  }
}

extern "C" void kernel_launch(void* const* d_in, const int* in_sizes, int n_in,
                              void* d_out, int out_size, void* d_ws,
                              size_t ws_size, hipStream_t stream) {
  const float* gen_img = (const float*)d_in[0];
  const float* target = (const float*)d_in[1];
  const float* gen_D = (const float*)d_in[2];
  float* out = (float*)d_out;
  float* ws = (float*)d_ws;

  dim3 grid(STRIPS, FRAMES);
  fused_kernel<<<grid, 256, 0, stream>>>(gen_img, target, ws);
  finalize_kernel<<<1, 256, 0, stream>>>(ws, gen_D, out);
}